// Round 4
// baseline (2046.148 us; speedup 1.0000x reference)
//
#include <hip/hip_runtime.h>

#define N_NODES 100000
#define N_EDGES 1280000
#define HID 64
#define N_ETYPE 8

// ---- workspace byte offsets (all 128B-aligned) ----
#define WS_HT    0ull            // Htn[n][512] f32 = 204,800,000 B
#define WS_MAGG  204800000ull    // N*64 f32   =  25,600,000 B
#define WS_OFFS  230400000ull    // N i32
#define WS_DEG   230800000ull    // N i32
#define WS_CUR   231200000ull    // N i32
#define WS_CSR   231600000ull    // E i32 = 5,120,000 B
#define WS_BSUM  236720000ull    // 128 i32
#define WS_BOFF  236720512ull    // 128 i32
// total ~236.8 MB

// ---------------------------------------------------------------------------
// K1 v3: Htn[n][t*64+m] = sum_h A[t][m][h] * h[n][h]
// Block = 4 waves, 64-node tile staged in LDS (coalesced once). Wave w owns
// types {2w, 2w+1}: A rows in 128 VGPRs. Inner: 16 uniform ds_read_b128 +
// 128 FMA per node. Fixes v2's 12.8M broadcast global loads + 8x h re-fetch.
// ---------------------------------------------------------------------------
#define K1_TILE 64
#define K1_NBLK 1563                   // ceil(100000/64)

__global__ __launch_bounds__(256, 3) void k1_ht(const float* __restrict__ h,
                                                const float* __restrict__ em,
                                                float* __restrict__ Htn) {
    __shared__ float hs[K1_TILE * HID];     // 16 KB
    int tid  = threadIdx.x;
    int lane = tid & 63;
    int w = __builtin_amdgcn_readfirstlane(tid >> 6);   // 0..3
    int t0 = 2 * w;

    // A[t0][lane][:], A[t0+1][lane][:] -> 128 VGPRs
    float a0[64], a1[64];
    {
        const float4* ar0 = (const float4*)(em + (size_t)t0 * 4096 + (size_t)lane * 64);
        const float4* ar1 = (const float4*)(em + (size_t)(t0 + 1) * 4096 + (size_t)lane * 64);
        #pragma unroll
        for (int q = 0; q < 16; ++q) {
            float4 v0 = ar0[q];
            a0[4*q+0] = v0.x; a0[4*q+1] = v0.y; a0[4*q+2] = v0.z; a0[4*q+3] = v0.w;
            float4 v1 = ar1[q];
            a1[4*q+0] = v1.x; a1[4*q+1] = v1.y; a1[4*q+2] = v1.z; a1[4*q+3] = v1.w;
        }
    }

    int n0 = blockIdx.x * K1_TILE;
    if (n0 >= N_NODES) return;
    int nn = N_NODES - n0; if (nn > K1_TILE) nn = K1_TILE;

    // stage h tile, coalesced float4
    {
        const float4* src = (const float4*)(h + (size_t)n0 * HID);
        float4* dst = (float4*)hs;
        int total4 = nn * (HID / 4);
        for (int i = tid; i < total4; i += 256) dst[i] = src[i];
    }
    __syncthreads();

    #pragma unroll 2
    for (int n = 0; n < nn; ++n) {
        const float4* hr = (const float4*)(hs + n * HID);
        float s0 = 0.f, s1 = 0.f, s2 = 0.f, s3 = 0.f;
        float r0 = 0.f, r1 = 0.f, r2 = 0.f, r3 = 0.f;
        #pragma unroll
        for (int q = 0; q < 16; ++q) {
            float4 v = hr[q];
            s0 = fmaf(a0[4*q+0], v.x, s0);
            s1 = fmaf(a0[4*q+1], v.y, s1);
            s2 = fmaf(a0[4*q+2], v.z, s2);
            s3 = fmaf(a0[4*q+3], v.w, s3);
            r0 = fmaf(a1[4*q+0], v.x, r0);
            r1 = fmaf(a1[4*q+1], v.y, r1);
            r2 = fmaf(a1[4*q+2], v.z, r2);
            r3 = fmaf(a1[4*q+3], v.w, r3);
        }
        size_t base = (size_t)(n0 + n) * 512 + (size_t)t0 * 64 + lane;
        Htn[base]      = (s0 + s1) + (s2 + s3);
        Htn[base + 64] = (r0 + r1) + (r2 + r3);
    }
}

// ---------------------------------------------------------------------------
// CSR build: histogram -> 2-level exclusive scan -> fill
// ---------------------------------------------------------------------------
__global__ void k_hist(const int* __restrict__ dst, int* __restrict__ deg) {
    int e = blockIdx.x * blockDim.x + threadIdx.x;
    if (e < N_EDGES) atomicAdd(&deg[dst[e]], 1);
}

__global__ void k_scan_a(const int* __restrict__ deg, int* __restrict__ offs,
                         int* __restrict__ bsum) {
    __shared__ int sh[256];
    int tid  = threadIdx.x;
    int base = blockIdx.x * 1024 + tid * 4;
    int d0 = (base + 0 < N_NODES) ? deg[base + 0] : 0;
    int d1 = (base + 1 < N_NODES) ? deg[base + 1] : 0;
    int d2 = (base + 2 < N_NODES) ? deg[base + 2] : 0;
    int d3 = (base + 3 < N_NODES) ? deg[base + 3] : 0;
    int s = d0 + d1 + d2 + d3;
    sh[tid] = s;
    __syncthreads();
    for (int ofs = 1; ofs < 256; ofs <<= 1) {
        int v = (tid >= ofs) ? sh[tid - ofs] : 0;
        __syncthreads();
        sh[tid] += v;
        __syncthreads();
    }
    int excl = sh[tid] - s;
    if (base + 0 < N_NODES) offs[base + 0] = excl;
    if (base + 1 < N_NODES) offs[base + 1] = excl + d0;
    if (base + 2 < N_NODES) offs[base + 2] = excl + d0 + d1;
    if (base + 3 < N_NODES) offs[base + 3] = excl + d0 + d1 + d2;
    if (tid == 255) bsum[blockIdx.x] = sh[255];
}

__global__ void k_scan_b(const int* __restrict__ bsum, int* __restrict__ boff) {
    __shared__ int sh[128];
    int tid = threadIdx.x;                 // 128 threads, NB = 98
    int v = (tid < 98) ? bsum[tid] : 0;
    sh[tid] = v;
    __syncthreads();
    for (int ofs = 1; ofs < 128; ofs <<= 1) {
        int u = (tid >= ofs) ? sh[tid - ofs] : 0;
        __syncthreads();
        sh[tid] += u;
        __syncthreads();
    }
    if (tid < 98) boff[tid] = sh[tid] - v;
}

__global__ void k_scan_c(int* __restrict__ offs, const int* __restrict__ boff,
                         int* __restrict__ cur) {
    int tid  = threadIdx.x;
    int add  = boff[blockIdx.x];
    int base = blockIdx.x * 1024 + tid * 4;
    #pragma unroll
    for (int q = 0; q < 4; ++q) {
        int i = base + q;
        if (i < N_NODES) { int v = offs[i] + add; offs[i] = v; cur[i] = v; }
    }
}

__global__ void k_fill(const int* __restrict__ src, const int* __restrict__ dst,
                       const int* __restrict__ typ, int* __restrict__ cur,
                       int* __restrict__ csr) {
    int e = blockIdx.x * blockDim.x + threadIdx.x;
    if (e < N_EDGES) {
        int d = dst[e];
        int p = atomicAdd(&cur[d], 1);
        csr[p] = (src[e] << 3) | typ[e];    // (src*8 + t) -> row of Htn[n][512]
    }
}

// ---------------------------------------------------------------------------
// K4: m_agg[d][m] = sum over in-edges of Htn[src][t*64+m]; wave per node.
// 4-deep unroll for memory-level parallelism on the random 256B gathers.
// ---------------------------------------------------------------------------
__global__ void k_agg(const float* __restrict__ Htn, const int* __restrict__ offs,
                      const int* __restrict__ deg, const int* __restrict__ csr,
                      float* __restrict__ magg) {
    int gwave = (int)((blockIdx.x * blockDim.x + threadIdx.x) >> 6);
    int lane  = threadIdx.x & 63;
    int d = __builtin_amdgcn_readfirstlane(gwave);
    if (d >= N_NODES) return;
    int off = offs[d];
    int cnt = deg[d];
    float acc0 = 0.f, acc1 = 0.f, acc2 = 0.f, acc3 = 0.f;
    int k = 0;
    for (; k + 3 < cnt; k += 4) {
        int i0 = csr[off + k + 0];
        int i1 = csr[off + k + 1];
        int i2 = csr[off + k + 2];
        int i3 = csr[off + k + 3];
        acc0 += Htn[(size_t)i0 * 64 + lane];
        acc1 += Htn[(size_t)i1 * 64 + lane];
        acc2 += Htn[(size_t)i2 * 64 + lane];
        acc3 += Htn[(size_t)i3 * 64 + lane];
    }
    for (; k < cnt; ++k) acc0 += Htn[(size_t)csr[off + k] * 64 + lane];
    magg[(size_t)d * HID + lane] = (acc0 + acc1) + (acc2 + acc3);
}

// ---------------------------------------------------------------------------
// K5 v2: fused GRU. Block = 3 waves, 16-node tile. magg+h tiles staged in
// LDS coalesced. Wave g holds w_ih AND w_hh rows g*64..g*64+63 (128 VGPRs),
// computes both matvecs per node; only r/z/i_n/h_n cross waves via LDS.
// ---------------------------------------------------------------------------
#define GRU_TILE 16

__global__ __launch_bounds__(192, 3) void k_gru(
        const float* __restrict__ h, const float* __restrict__ magg,
        const float* __restrict__ w_ih, const float* __restrict__ w_hh,
        const float* __restrict__ b_ih, const float* __restrict__ b_hh,
        float* __restrict__ out) {
    __shared__ float ms[GRU_TILE * HID];    // 4 KB  magg tile
    __shared__ float hsh[GRU_TILE * HID];   // 4 KB  h tile
    __shared__ float r_s[GRU_TILE * HID];   // 4 KB
    __shared__ float z_s[GRU_TILE * HID];
    __shared__ float in_s[GRU_TILE * HID];
    __shared__ float hn_s[GRU_TILE * HID];  // total 24 KB

    int tid  = threadIdx.x;
    int lane = tid & 63;
    int g = __builtin_amdgcn_readfirstlane(tid >> 6);   // 0..2 gate

    // weights: rows g*64+lane of w_ih and w_hh -> 128 VGPRs
    float wi[64], wh[64];
    {
        const float4* wri = (const float4*)(w_ih + (size_t)(g * 64 + lane) * 64);
        const float4* wrh = (const float4*)(w_hh + (size_t)(g * 64 + lane) * 64);
        #pragma unroll
        for (int q = 0; q < 16; ++q) {
            float4 a = wri[q];
            wi[4*q+0] = a.x; wi[4*q+1] = a.y; wi[4*q+2] = a.z; wi[4*q+3] = a.w;
            float4 b = wrh[q];
            wh[4*q+0] = b.x; wh[4*q+1] = b.y; wh[4*q+2] = b.z; wh[4*q+3] = b.w;
        }
    }
    float bi = b_ih[g * 64 + lane];
    float bh = b_hh[g * 64 + lane];

    int n0 = blockIdx.x * GRU_TILE;     // 6250 blocks, exact

    // stage magg + h tiles coalesced
    {
        const float4* sm = (const float4*)(magg + (size_t)n0 * HID);
        const float4* sh4 = (const float4*)(h + (size_t)n0 * HID);
        float4* dm = (float4*)ms;
        float4* dh = (float4*)hsh;
        for (int i = tid; i < GRU_TILE * HID / 4; i += 192) { dm[i] = sm[i]; dh[i] = sh4[i]; }
    }
    __syncthreads();

    #pragma unroll 2
    for (int n = 0; n < GRU_TILE; ++n) {
        const float4* vm = (const float4*)(ms + n * HID);
        const float4* vh = (const float4*)(hsh + n * HID);
        float i0 = bi, i1 = 0.f, i2 = 0.f, i3 = 0.f;
        float h0 = bh, h1 = 0.f, h2 = 0.f, h3 = 0.f;
        #pragma unroll
        for (int q = 0; q < 16; ++q) {
            float4 a = vm[q];
            i0 = fmaf(wi[4*q+0], a.x, i0);
            i1 = fmaf(wi[4*q+1], a.y, i1);
            i2 = fmaf(wi[4*q+2], a.z, i2);
            i3 = fmaf(wi[4*q+3], a.w, i3);
            float4 b = vh[q];
            h0 = fmaf(wh[4*q+0], b.x, h0);
            h1 = fmaf(wh[4*q+1], b.y, h1);
            h2 = fmaf(wh[4*q+2], b.z, h2);
            h3 = fmaf(wh[4*q+3], b.w, h3);
        }
        float si = (i0 + i1) + (i2 + i3);
        float sh = (h0 + h1) + (h2 + h3);
        if (g == 0)      r_s[n * HID + lane] = 1.f / (1.f + __expf(-(si + sh)));
        else if (g == 1) z_s[n * HID + lane] = 1.f / (1.f + __expf(-(si + sh)));
        else           { in_s[n * HID + lane] = si; hn_s[n * HID + lane] = sh; }
    }
    __syncthreads();

    for (int idx = tid; idx < GRU_TILE * HID; idx += 192) {
        float r  = r_s[idx];
        float z  = z_s[idx];
        float nn = tanhf(in_s[idx] + r * hn_s[idx]);
        float hv = h[(size_t)n0 * HID + idx];
        out[(size_t)n0 * HID + idx] = (1.f - z) * nn + z * hv;
    }
}

// ---------------------------------------------------------------------------
extern "C" void kernel_launch(void* const* d_in, const int* in_sizes, int n_in,
                              void* d_out, int out_size, void* d_ws, size_t ws_size,
                              hipStream_t stream) {
    const float* h    = (const float*)d_in[0];
    const float* em   = (const float*)d_in[1];
    const float* w_ih = (const float*)d_in[2];
    const float* w_hh = (const float*)d_in[3];
    const float* b_ih = (const float*)d_in[4];
    const float* b_hh = (const float*)d_in[5];
    const int* e_src  = (const int*)d_in[6];
    const int* e_dst  = (const int*)d_in[7];
    const int* e_typ  = (const int*)d_in[8];
    float* out = (float*)d_out;

    char* ws = (char*)d_ws;
    float* Htn  = (float*)(ws + WS_HT);
    float* magg = (float*)(ws + WS_MAGG);
    int* offs = (int*)(ws + WS_OFFS);
    int* deg  = (int*)(ws + WS_DEG);
    int* cur  = (int*)(ws + WS_CUR);
    int* csr  = (int*)(ws + WS_CSR);
    int* bsum = (int*)(ws + WS_BSUM);
    int* boff = (int*)(ws + WS_BOFF);

    hipMemsetAsync(deg, 0, (size_t)N_NODES * sizeof(int), stream);

    // Ht GEMM: 1563 blocks x 64-node tiles
    k1_ht<<<K1_NBLK, 256, 0, stream>>>(h, em, Htn);

    // CSR build
    k_hist<<<N_EDGES / 256, 256, 0, stream>>>(e_dst, deg);
    k_scan_a<<<98, 256, 0, stream>>>(deg, offs, bsum);
    k_scan_b<<<1, 128, 0, stream>>>(bsum, boff);
    k_scan_c<<<98, 256, 0, stream>>>(offs, boff, cur);
    k_fill<<<N_EDGES / 256, 256, 0, stream>>>(e_src, e_dst, e_typ, cur, csr);

    // aggregate: 100000 waves, 4 waves/block
    k_agg<<<25000, 256, 0, stream>>>(Htn, offs, deg, csr, magg);

    // fused GRU: 6250 blocks x 16-node tiles
    k_gru<<<N_NODES / GRU_TILE, 192, 0, stream>>>(h, magg, w_ih, w_hh, b_ih, b_hh, out);
}

// Round 6
// 764.118 us; speedup vs baseline: 2.6778x; 2.6778x over previous
//
#include <hip/hip_runtime.h>

#define N_NODES 100000
#define N_EDGES 1280000
#define HID 64
#define N_ETYPE 8

// ---- workspace byte offsets (all 128B-aligned) ----
#define WS_HT    0ull            // Htn[n][512] f32 = 204,800,000 B
#define WS_MAGG  204800000ull    // N*64 f32   =  25,600,000 B
#define WS_OFFS  230400000ull    // N i32
#define WS_DEG   230800000ull    // N i32
#define WS_CUR   231200000ull    // N i32
#define WS_CSR   231600000ull    // E i32 = 5,120,000 B
#define WS_BSUM  236720000ull    // 128 i32
#define WS_BOFF  236720512ull    // 128 i32
// total ~236.8 MB

// ---------------------------------------------------------------------------
// K1 v4: Htn[n][t*64+m] = sum_h A[t][m][h] * h[n][h]
// Block = 8 waves (512 thr), wave w owns type w: ONE a[64] per lane (~90
// VGPR, no spill — v3 spilled at 128 floats under a 170-VGPR cap: FETCH
// 3.4GB of scratch traffic). 64-node h tile staged once in LDS, broadcast
// ds_reads inner; stores coalesced (8 waves cover the 2KB Htn row).
// ---------------------------------------------------------------------------
#define K1_TILE 64
#define K1_NBLK 1563                   // ceil(100000/64)

__global__ __launch_bounds__(512, 2) void k1_ht(const float* __restrict__ h,
                                                const float* __restrict__ em,
                                                float* __restrict__ Htn) {
    __shared__ float hs[K1_TILE * HID];     // 16 KB
    int tid  = threadIdx.x;
    int lane = tid & 63;
    int t = __builtin_amdgcn_readfirstlane(tid >> 6);   // 0..7 = edge type

    // A[t][lane][:] -> 64 VGPRs
    float a[64];
    {
        const float4* ar = (const float4*)(em + (size_t)t * 4096 + (size_t)lane * 64);
        #pragma unroll
        for (int q = 0; q < 16; ++q) {
            float4 v = ar[q];
            a[4*q+0] = v.x; a[4*q+1] = v.y; a[4*q+2] = v.z; a[4*q+3] = v.w;
        }
    }

    int n0 = blockIdx.x * K1_TILE;
    if (n0 >= N_NODES) return;
    int nn = N_NODES - n0; if (nn > K1_TILE) nn = K1_TILE;

    // stage h tile, coalesced float4
    {
        const float4* src = (const float4*)(h + (size_t)n0 * HID);
        float4* dst = (float4*)hs;
        int total4 = nn * (HID / 4);
        for (int i = tid; i < total4; i += 512) dst[i] = src[i];
    }
    __syncthreads();

    #pragma unroll 2
    for (int n = 0; n < nn; ++n) {
        const float4* hr = (const float4*)(hs + n * HID);
        float s0 = 0.f, s1 = 0.f, s2 = 0.f, s3 = 0.f;
        #pragma unroll
        for (int q = 0; q < 16; ++q) {
            float4 v = hr[q];
            s0 = fmaf(a[4*q+0], v.x, s0);
            s1 = fmaf(a[4*q+1], v.y, s1);
            s2 = fmaf(a[4*q+2], v.z, s2);
            s3 = fmaf(a[4*q+3], v.w, s3);
        }
        Htn[(size_t)(n0 + n) * 512 + (size_t)t * 64 + lane] = (s0 + s1) + (s2 + s3);
    }
}

// ---------------------------------------------------------------------------
// CSR build: histogram -> 2-level exclusive scan -> fill
// ---------------------------------------------------------------------------
__global__ void k_hist(const int* __restrict__ dst, int* __restrict__ deg) {
    int e = blockIdx.x * blockDim.x + threadIdx.x;
    if (e < N_EDGES) atomicAdd(&deg[dst[e]], 1);
}

__global__ void k_scan_a(const int* __restrict__ deg, int* __restrict__ offs,
                         int* __restrict__ bsum) {
    __shared__ int sh[256];
    int tid  = threadIdx.x;
    int base = blockIdx.x * 1024 + tid * 4;
    int d0 = (base + 0 < N_NODES) ? deg[base + 0] : 0;
    int d1 = (base + 1 < N_NODES) ? deg[base + 1] : 0;
    int d2 = (base + 2 < N_NODES) ? deg[base + 2] : 0;
    int d3 = (base + 3 < N_NODES) ? deg[base + 3] : 0;
    int s = d0 + d1 + d2 + d3;
    sh[tid] = s;
    __syncthreads();
    for (int ofs = 1; ofs < 256; ofs <<= 1) {
        int v = (tid >= ofs) ? sh[tid - ofs] : 0;
        __syncthreads();
        sh[tid] += v;
        __syncthreads();
    }
    int excl = sh[tid] - s;
    if (base + 0 < N_NODES) offs[base + 0] = excl;
    if (base + 1 < N_NODES) offs[base + 1] = excl + d0;
    if (base + 2 < N_NODES) offs[base + 2] = excl + d0 + d1;
    if (base + 3 < N_NODES) offs[base + 3] = excl + d0 + d1 + d2;
    if (tid == 255) bsum[blockIdx.x] = sh[255];
}

__global__ void k_scan_b(const int* __restrict__ bsum, int* __restrict__ boff) {
    __shared__ int sh[128];
    int tid = threadIdx.x;                 // 128 threads, NB = 98
    int v = (tid < 98) ? bsum[tid] : 0;
    sh[tid] = v;
    __syncthreads();
    for (int ofs = 1; ofs < 128; ofs <<= 1) {
        int u = (tid >= ofs) ? sh[tid - ofs] : 0;
        __syncthreads();
        sh[tid] += u;
        __syncthreads();
    }
    if (tid < 98) boff[tid] = sh[tid] - v;
}

__global__ void k_scan_c(int* __restrict__ offs, const int* __restrict__ boff,
                         int* __restrict__ cur) {
    int tid  = threadIdx.x;
    int add  = boff[blockIdx.x];
    int base = blockIdx.x * 1024 + tid * 4;
    #pragma unroll
    for (int q = 0; q < 4; ++q) {
        int i = base + q;
        if (i < N_NODES) { int v = offs[i] + add; offs[i] = v; cur[i] = v; }
    }
}

__global__ void k_fill(const int* __restrict__ src, const int* __restrict__ dst,
                       const int* __restrict__ typ, int* __restrict__ cur,
                       int* __restrict__ csr) {
    int e = blockIdx.x * blockDim.x + threadIdx.x;
    if (e < N_EDGES) {
        int d = dst[e];
        int p = atomicAdd(&cur[d], 1);
        csr[p] = (src[e] << 3) | typ[e];    // (src*8 + t) -> row of Htn[n][512]
    }
}

// ---------------------------------------------------------------------------
// K4: m_agg[d][m] = sum over in-edges of Htn[src*8+t][m]; wave per node.
// 4-deep unroll for memory-level parallelism on the random 256B gathers.
// ---------------------------------------------------------------------------
__global__ void k_agg(const float* __restrict__ Htn, const int* __restrict__ offs,
                      const int* __restrict__ deg, const int* __restrict__ csr,
                      float* __restrict__ magg) {
    int gwave = (int)((blockIdx.x * blockDim.x + threadIdx.x) >> 6);
    int lane  = threadIdx.x & 63;
    int d = __builtin_amdgcn_readfirstlane(gwave);
    if (d >= N_NODES) return;
    int off = offs[d];
    int cnt = deg[d];
    float acc0 = 0.f, acc1 = 0.f, acc2 = 0.f, acc3 = 0.f;
    int k = 0;
    for (; k + 3 < cnt; k += 4) {
        int i0 = csr[off + k + 0];
        int i1 = csr[off + k + 1];
        int i2 = csr[off + k + 2];
        int i3 = csr[off + k + 3];
        acc0 += Htn[(size_t)i0 * 64 + lane];
        acc1 += Htn[(size_t)i1 * 64 + lane];
        acc2 += Htn[(size_t)i2 * 64 + lane];
        acc3 += Htn[(size_t)i3 * 64 + lane];
    }
    for (; k < cnt; ++k) acc0 += Htn[(size_t)csr[off + k] * 64 + lane];
    magg[(size_t)d * HID + lane] = (acc0 + acc1) + (acc2 + acc3);
}

// ---------------------------------------------------------------------------
// K5 v3: fused GRU. 6 waves (384 thr); wave g owns ONE weight matrix's rows
// g*64..g*64+63 (64 VGPRs each — spill-safe, unlike the 128-float variant).
// magg+h tiles staged in LDS; gate pieces exchanged through LDS.
// ---------------------------------------------------------------------------
#define GRU_TILE 16

__global__ __launch_bounds__(384, 2) void k_gru(
        const float* __restrict__ h, const float* __restrict__ magg,
        const float* __restrict__ w_ih, const float* __restrict__ w_hh,
        const float* __restrict__ b_ih, const float* __restrict__ b_hh,
        float* __restrict__ out) {
    __shared__ float ms[GRU_TILE * HID];     // 4 KB  magg tile
    __shared__ float hsh[GRU_TILE * HID];    // 4 KB  h tile
    __shared__ float g_lds[6][GRU_TILE * HID]; // 24 KB gate pieces

    int tid  = threadIdx.x;
    int lane = tid & 63;
    int g = __builtin_amdgcn_readfirstlane(tid >> 6);   // 0..5

    const float* wrow = (g < 3) ? (w_ih + (size_t)(g * 64 + lane) * 64)
                                : (w_hh + (size_t)((g - 3) * 64 + lane) * 64);
    float w[64];
    {
        const float4* wr4 = (const float4*)wrow;
        #pragma unroll
        for (int q = 0; q < 16; ++q) {
            float4 v = wr4[q];
            w[4*q+0] = v.x; w[4*q+1] = v.y; w[4*q+2] = v.z; w[4*q+3] = v.w;
        }
    }
    float bias = (g < 3) ? b_ih[g * 64 + lane] : b_hh[(g - 3) * 64 + lane];

    int n0 = blockIdx.x * GRU_TILE;     // 6250 blocks, exact

    // stage magg + h tiles coalesced
    {
        const float4* sm  = (const float4*)(magg + (size_t)n0 * HID);
        const float4* sh4 = (const float4*)(h + (size_t)n0 * HID);
        float4* dm = (float4*)ms;
        float4* dh = (float4*)hsh;
        for (int i = tid; i < GRU_TILE * HID / 4; i += 384) { dm[i] = sm[i]; dh[i] = sh4[i]; }
    }
    __syncthreads();

    const float* vin = (g < 3) ? ms : hsh;
    #pragma unroll 2
    for (int n = 0; n < GRU_TILE; ++n) {
        const float4* vr = (const float4*)(vin + n * HID);
        float s0 = bias, s1 = 0.f, s2 = 0.f, s3 = 0.f;
        #pragma unroll
        for (int q = 0; q < 16; ++q) {
            float4 v = vr[q];
            s0 = fmaf(w[4*q+0], v.x, s0);
            s1 = fmaf(w[4*q+1], v.y, s1);
            s2 = fmaf(w[4*q+2], v.z, s2);
            s3 = fmaf(w[4*q+3], v.w, s3);
        }
        g_lds[g][n * HID + lane] = (s0 + s1) + (s2 + s3);
    }
    __syncthreads();

    for (int idx = tid; idx < GRU_TILE * HID; idx += 384) {
        float gir = g_lds[0][idx], giz = g_lds[1][idx], gin = g_lds[2][idx];
        float ghr = g_lds[3][idx], ghz = g_lds[4][idx], ghn = g_lds[5][idx];
        float hv  = hsh[idx];
        float r  = 1.f / (1.f + __expf(-(gir + ghr)));
        float z  = 1.f / (1.f + __expf(-(giz + ghz)));
        float nn = tanhf(gin + r * ghn);
        out[(size_t)n0 * HID + idx] = (1.f - z) * nn + z * hv;
    }
}

// ---------------------------------------------------------------------------
extern "C" void kernel_launch(void* const* d_in, const int* in_sizes, int n_in,
                              void* d_out, int out_size, void* d_ws, size_t ws_size,
                              hipStream_t stream) {
    const float* h    = (const float*)d_in[0];
    const float* em   = (const float*)d_in[1];
    const float* w_ih = (const float*)d_in[2];
    const float* w_hh = (const float*)d_in[3];
    const float* b_ih = (const float*)d_in[4];
    const float* b_hh = (const float*)d_in[5];
    const int* e_src  = (const int*)d_in[6];
    const int* e_dst  = (const int*)d_in[7];
    const int* e_typ  = (const int*)d_in[8];
    float* out = (float*)d_out;

    char* ws = (char*)d_ws;
    float* Htn  = (float*)(ws + WS_HT);
    float* magg = (float*)(ws + WS_MAGG);
    int* offs = (int*)(ws + WS_OFFS);
    int* deg  = (int*)(ws + WS_DEG);
    int* cur  = (int*)(ws + WS_CUR);
    int* csr  = (int*)(ws + WS_CSR);
    int* bsum = (int*)(ws + WS_BSUM);
    int* boff = (int*)(ws + WS_BOFF);

    hipMemsetAsync(deg, 0, (size_t)N_NODES * sizeof(int), stream);

    // Ht GEMM: 1563 blocks x 64-node tiles, 8 waves (one type each)
    k1_ht<<<K1_NBLK, 512, 0, stream>>>(h, em, Htn);

    // CSR build
    k_hist<<<N_EDGES / 256, 256, 0, stream>>>(e_dst, deg);
    k_scan_a<<<98, 256, 0, stream>>>(deg, offs, bsum);
    k_scan_b<<<1, 128, 0, stream>>>(bsum, boff);
    k_scan_c<<<98, 256, 0, stream>>>(offs, boff, cur);
    k_fill<<<N_EDGES / 256, 256, 0, stream>>>(e_src, e_dst, e_typ, cur, csr);

    // aggregate: 100000 waves, 4 waves/block
    k_agg<<<25000, 256, 0, stream>>>(Htn, offs, deg, csr, magg);

    // fused GRU: 6250 blocks x 16-node tiles
    k_gru<<<N_NODES / GRU_TILE, 384, 0, stream>>>(h, magg, w_ih, w_hh, b_ih, b_hh, out);
}